// Round 19
// baseline (37.430 us; speedup 1.0000x reference)
//
#include <hip/hip_runtime.h>
#include <hip/hip_bf16.h>

// LogicConv3d: B=64, C=32, H=32, W=32, K=64, P=784, S=16 gathers/side.
// R19: 8 waves/SIMD via natural-64-VGPR + 72KB p-half tile + role-split.
//  - R13/R15 lesson: NEVER force occupancy with launch_bounds min-arg
//    (allocator strangles to 32 VGPR -> spills). R10/R12's pair-granularity
//    body hits 64 VGPR NATURALLY = the 8-waves/SIMD threshold (m69).
//  - R15 geometry: p-rows [14ph,14ph+14) need image rows [14ph,14ph+18)
//    = 72KB -> 2 blocks/CU (144KB LDS) -> 32 waves/CU, 2x R18's hiding.
//  - R18 role split kept: 8 waves gather even image from LDS (ds pipe),
//    8 waves gather odd image from L2 (vmem pipe), mixed across SIMDs.
//  - Quartered transients (ev[16]/od[16]) keep natural VGPR <= 64.
//  - Grid 512 = 32bp x 2ph x 8kg, bp fastest (XCD L2 locality), all
//    resident in exactly one round.

#define B_  64
#define C_  32
#define H_  32
#define W_  32
#define K_  64
#define P_  784
#define CHW (C_*H_*W_)      // 32768 floats
#define HW  (H_*W_)         // 1024
#define SITES (K_*P_)       // 50176
#define NPAIRH 196          // pairs per p-half
#define NROWS 18
#define TILEF (C_*NROWS*W_) // 18432 floats = 72 KB

__constant__ float COEF_[16][4] = {
    {0, 0, 0, 0}, {0, 0, 0, 1}, {0, 1, 0, -1}, {0, 1, 0, 0},
    {0, 0, 1, -1}, {0, 0, 1, 0}, {0, 1, 1, -2}, {0, 1, 1, -1},
    {1, -1, -1, 1}, {1, -1, -1, 2}, {1, 0, -1, 0}, {1, 0, -1, 1},
    {1, -1, 0, 0}, {1, -1, 0, 1}, {1, 0, 0, -1}, {1, 0, 0, 0}
};

typedef float f2u __attribute__((ext_vector_type(2), aligned(4)));

// ---- kernel 1: prep = baseG/baseL (0..2047) + coefs (2048..4031) ----
__global__ __launch_bounds__(256) void prep_kernel(
    const int* __restrict__ a_idx, const int* __restrict__ b_idx,
    const float* __restrict__ w0, const float* __restrict__ w1,
    const float* __restrict__ w2, const float* __restrict__ w3,
    const float* __restrict__ w4,
    int* __restrict__ baseG,         // [K_][32] bytes, full image
    int* __restrict__ baseL,         // [K_][32] bytes, 18-row tile
    float4* __restrict__ cws)        // [K_*31]
{
    const int t = blockIdx.x * 256 + threadIdx.x;
    if (t < K_ * 32) {
        const int k = t >> 5;
        const int j = t & 31;
        const int* src = (j < 16) ? a_idx : b_idx;
        const int l = j & 15;
        const size_t ii = ((size_t)k * P_ * 16 + l) * 3;   // site (k, p=0, l)
        const int h = src[ii + 0];   // h_off (hg=0 at p=0)
        const int w = src[ii + 1];   // w_off
        const int c = src[ii + 2];
        baseG[t] = (c << 12) + (h << 7) + (w << 2);
        baseL[t] = c * 2304 + (h << 7) + (w << 2);   // c*576 floats
    } else if (t < K_ * 32 + K_ * 31) {
        const int tt = t - K_ * 32;
        const int k = tt / 31;
        const int node = tt - k * 31;
        int d, l;
        if      (node < 16) { d = 0; l = node; }
        else if (node < 24) { d = 1; l = node - 16; }
        else if (node < 28) { d = 2; l = node - 24; }
        else if (node < 30) { d = 3; l = node - 28; }
        else                { d = 4; l = 0; }
        const float* W;
        switch (d) {
            case 0: W = w0; break;
            case 1: W = w1; break;
            case 2: W = w2; break;
            case 3: W = w3; break;
            default: W = w4; break;
        }
        const float* row = W + ((size_t)l * K_ + k) * 16;
        float m = row[0];
        #pragma unroll
        for (int o = 1; o < 16; ++o) m = fmaxf(m, row[o]);
        float e[16];
        float Z = 0.0f;
        #pragma unroll
        for (int o = 0; o < 16; ++o) { e[o] = expf(row[o] - m); Z += e[o]; }
        const float inv = 1.0f / Z;
        float c0 = 0.f, c1 = 0.f, c2 = 0.f, c3 = 0.f;
        #pragma unroll
        for (int o = 0; o < 16; ++o) {
            c0 += e[o] * COEF_[o][0];
            c1 += e[o] * COEF_[o][1];
            c2 += e[o] * COEF_[o][2];
            c3 += e[o] * COEF_[o][3];
        }
        cws[tt] = make_float4(c0 * inv, c1 * inv, c2 * inv, c3 * inv);
    }
}

// y = c0 + c1*a + c2*b + c3*a*b == fma(b, fma(c3,a,c2), fma(c1,a,c0))
__device__ __forceinline__ float binop(float a, float b, float4 c) {
    return fmaf(b, fmaf(c.w, a, c.z), fmaf(c.y, a, c.x));
}

// ---- kernel 2: main. bid = ((kg*2+ph)<<5)|bp. 1024 thr, 2 blocks/CU. ----
__global__ __launch_bounds__(1024) void logicconv_main(
    const float* __restrict__ x,
    const int* __restrict__ baseG,
    const int* __restrict__ baseL,
    const float4* __restrict__ cws,
    float* __restrict__ out)
{
    __shared__ float simg[TILEF];   // 72 KB: even-image rows [14ph, 14ph+18)

    const int tid = threadIdx.x;
    const int bid = blockIdx.x;
    const int bp  = bid & 31;          // fastest
    const int ph  = (bid >> 5) & 1;    // p-half
    const int kg  = bid >> 6;          // 0..7
    const int b0  = bp * 2;
    const int rlo = 14 * ph;

    // ---- stage even-image rows [rlo, rlo+18), all 32 channels ----
    {
        const float4* xi = (const float4*)(x + (size_t)b0 * CHW + rlo * W_);
        float4* si = (float4*)simg;
        #pragma unroll
        for (int it = 0; it < 5; ++it) {
            const int u = it * 1024 + tid;     // < 4608
            if (u < 4608) {
                const int c = u / 144;         // channel
                const int j = u - c * 144;     // f4 within channel tile
                si[u] = xi[c * 256 + j];
            }
        }
    }
    __syncthreads();

    // ---- role split: 8 even-role waves (LDS), 8 odd-role (global) ----
    const int w    = __builtin_amdgcn_readfirstlane(tid >> 6);   // 0..15
    const int lane = tid & 63;
    const int isOdd = (w >> 2) & 1;
    const int kloc  = (w & 3) | ((w >> 3) << 2);    // 0..7
    const int k     = kg * 8 + kloc;

    const float4* __restrict__ cw = cws + (size_t)k * 31;     // s_load

    if (!isOdd) {
        // ======== EVEN image from LDS tile ========
        const int* __restrict__ bL = baseL + k * 32;          // s_load
        const char* sb = (const char*)simg;
        float* __restrict__ o0 = out + ((size_t)b0 * K_ + k) * P_ + 392 * ph;
        for (int s = 0; s < 4; ++s) {
            const int t = s * 64 + lane;           // local pair index
            if (t < NPAIRH) {
                const unsigned disp = 8u * (unsigned)t + 16u * ((unsigned)t / 14u);
                float2 y1[8];
                #pragma unroll
                for (int q = 0; q < 4; ++q) {      // quarters of 4 leaves
                    float ev[16];
                    #pragma unroll
                    for (int j = 0; j < 4; ++j) {
                        const int l = q * 4 + j;
                        const unsigned la = (unsigned)bL[l]      + disp;
                        const unsigned lb = (unsigned)bL[16 + l] + disp;
                        ev[4*j+0] = *(const float*)(sb + la);
                        ev[4*j+1] = *(const float*)(sb + la + 4);
                        ev[4*j+2] = *(const float*)(sb + lb);
                        ev[4*j+3] = *(const float*)(sb + lb + 4);
                    }
                    #pragma unroll
                    for (int j = 0; j < 2; ++j) {  // layer0 + layer1 folded
                        const int l0 = q * 4 + 2 * j;
                        const int n  = q * 2 + j;
                        const float4 cA = cw[l0], cB = cw[l0 + 1];
                        const float4 cL = cw[16 + n];
                        const float z0x = binop(ev[8*j+0], ev[8*j+2], cA);
                        const float z0y = binop(ev[8*j+1], ev[8*j+3], cA);
                        const float z1x = binop(ev[8*j+4], ev[8*j+6], cB);
                        const float z1y = binop(ev[8*j+5], ev[8*j+7], cB);
                        y1[n].x = binop(z0x, z1x, cL);
                        y1[n].y = binop(z0y, z1y, cL);
                    }
                }
                float2 y2[4];
                #pragma unroll
                for (int l = 0; l < 4; ++l) {
                    const float4 c = cw[24 + l];
                    y2[l].x = binop(y1[2*l].x, y1[2*l+1].x, c);
                    y2[l].y = binop(y1[2*l].y, y1[2*l+1].y, c);
                }
                float2 y3[2];
                #pragma unroll
                for (int l = 0; l < 2; ++l) {
                    const float4 c = cw[28 + l];
                    y3[l].x = binop(y2[2*l].x, y2[2*l+1].x, c);
                    y3[l].y = binop(y2[2*l].y, y2[2*l+1].y, c);
                }
                const float4 c4 = cw[30];
                float2 re;
                re.x = binop(y3[0].x, y3[1].x, c4);
                re.y = binop(y3[0].y, y3[1].y, c4);
                *(float2*)(o0 + 2 * t) = re;
            }
        }
    } else {
        // ======== ODD image from global (L2) ========
        const int* __restrict__ bG = baseG + k * 32;          // s_load
        const char* x1 = (const char*)(x + (size_t)(b0 + 1) * CHW) + 1792 * ph;
        float* __restrict__ o1 = out + ((size_t)(b0 + 1) * K_ + k) * P_ + 392 * ph;
        for (int s = 0; s < 4; ++s) {
            const int t = s * 64 + lane;           // local pair index
            if (t < NPAIRH) {
                const unsigned disp = 8u * (unsigned)t + 16u * ((unsigned)t / 14u);
                float2 y1[8];
                #pragma unroll
                for (int q = 0; q < 4; ++q) {      // quarters of 4 leaves
                    float od[16];
                    #pragma unroll
                    for (int j = 0; j < 4; ++j) {
                        const int l = q * 4 + j;
                        const f2u va = *(const f2u*)(x1 + ((unsigned)bG[l]      + disp));
                        const f2u vb = *(const f2u*)(x1 + ((unsigned)bG[16 + l] + disp));
                        od[4*j+0] = va.x;
                        od[4*j+1] = va.y;
                        od[4*j+2] = vb.x;
                        od[4*j+3] = vb.y;
                    }
                    #pragma unroll
                    for (int j = 0; j < 2; ++j) {  // layer0 + layer1 folded
                        const int l0 = q * 4 + 2 * j;
                        const int n  = q * 2 + j;
                        const float4 cA = cw[l0], cB = cw[l0 + 1];
                        const float4 cL = cw[16 + n];
                        const float z0x = binop(od[8*j+0], od[8*j+2], cA);
                        const float z0y = binop(od[8*j+1], od[8*j+3], cA);
                        const float z1x = binop(od[8*j+4], od[8*j+6], cB);
                        const float z1y = binop(od[8*j+5], od[8*j+7], cB);
                        y1[n].x = binop(z0x, z1x, cL);
                        y1[n].y = binop(z0y, z1y, cL);
                    }
                }
                float2 y2[4];
                #pragma unroll
                for (int l = 0; l < 4; ++l) {
                    const float4 c = cw[24 + l];
                    y2[l].x = binop(y1[2*l].x, y1[2*l+1].x, c);
                    y2[l].y = binop(y1[2*l].y, y1[2*l+1].y, c);
                }
                float2 y3[2];
                #pragma unroll
                for (int l = 0; l < 2; ++l) {
                    const float4 c = cw[28 + l];
                    y3[l].x = binop(y2[2*l].x, y2[2*l+1].x, c);
                    y3[l].y = binop(y2[2*l].y, y2[2*l+1].y, c);
                }
                const float4 c4 = cw[30];
                float2 ro;
                ro.x = binop(y3[0].x, y3[1].x, c4);
                ro.y = binop(y3[0].y, y3[1].y, c4);
                *(float2*)(o1 + 2 * t) = ro;
            }
        }
    }
}

extern "C" void kernel_launch(void* const* d_in, const int* in_sizes, int n_in,
                              void* d_out, int out_size, void* d_ws, size_t ws_size,
                              hipStream_t stream) {
    const float* x     = (const float*)d_in[0];
    const float* w0    = (const float*)d_in[1];
    const float* w1    = (const float*)d_in[2];
    const float* w2    = (const float*)d_in[3];
    const float* w3    = (const float*)d_in[4];
    const float* w4    = (const float*)d_in[5];
    const int*   a_idx = (const int*)d_in[6];
    const int*   b_idx = (const int*)d_in[7];
    float* out = (float*)d_out;

    // ws layout: baseG (8 KB) | baseL (8 KB) | cws (32 KB)
    int*    baseG = (int*)d_ws;
    int*    baseL = baseG + K_ * 32;
    float4* cws   = (float4*)(baseL + K_ * 32);

    prep_kernel<<<16, 256, 0, stream>>>(a_idx, b_idx, w0, w1, w2, w3, w4,
                                        baseG, baseL, cws);

    logicconv_main<<<512, 1024, 0, stream>>>(x, baseG, baseL, cws, out);
}